// Round 1
// baseline (481.979 us; speedup 1.0000x reference)
//
#include <hip/hip_runtime.h>

// ---------- types ----------
typedef __attribute__((ext_vector_type(8))) __bf16 bf16x8;
typedef __attribute__((ext_vector_type(8))) unsigned short us8;
typedef __attribute__((ext_vector_type(4))) float f32x4;

#define DEV __device__ __forceinline__

DEV unsigned short f2bf(float f) {
    unsigned u = __builtin_bit_cast(unsigned, f);
    u += 0x7fffu + ((u >> 16) & 1u);
    return (unsigned short)(u >> 16);
}
DEV float bf2f(unsigned short h) {
    return __builtin_bit_cast(float, (unsigned)h << 16);
}

DEV void gload_lds16(const void* g, void* l) {
    __builtin_amdgcn_global_load_lds(
        (const __attribute__((address_space(1))) unsigned int*)g,
        (__attribute__((address_space(3))) unsigned int*)l, 16, 0, 0);
}

// ---------- GEMM: C[M,N] = A[M,K] * B[N,K]^T, bf16 in, fp32 acc ----------
// EPI 0: bf16 store; 1: fp32 store; 2: relu(x+bias) bf16 store
template <int EPI>
__global__ __launch_bounds__(256, 2) void gemm_bt(
    const unsigned short* __restrict__ A, const unsigned short* __restrict__ B,
    void* __restrict__ Cv, const float* __restrict__ bias, int M, int N, int K) {
    __shared__ __attribute__((aligned(16))) unsigned short As[128 * 64];
    __shared__ __attribute__((aligned(16))) unsigned short Bs[128 * 64];
    const int tid = threadIdx.x;
    const int m0 = blockIdx.y * 128;
    const int n0 = blockIdx.x * 128;
    const int wave = tid >> 6;
    const int wr = (wave >> 1) * 64, wc = (wave & 1) * 64;
    const int r = tid & 15;        // lane & 15
    const int g = (tid >> 4) & 3;  // lane >> 4

    f32x4 acc[4][4] = {};
    const unsigned short* Ag = A + (size_t)m0 * K;
    const unsigned short* Bg = B + (size_t)n0 * K;

    for (int k0 = 0; k0 < K; k0 += 64) {
#pragma unroll
        for (int c = 0; c < 4; ++c) {
            int e = c * 2048 + tid * 8;
            int row = e >> 6, col = e & 63;
            gload_lds16(Ag + row * K + (k0 + col), (char*)As + e * 2);
            gload_lds16(Bg + row * K + (k0 + col), (char*)Bs + e * 2);
        }
        __syncthreads();
#pragma unroll
        for (int kk = 0; kk < 2; ++kk) {
            bf16x8 av[4], bv[4];
#pragma unroll
            for (int i = 0; i < 4; ++i)
                av[i] = *(const bf16x8*)(As + (wr + i * 16 + r) * 64 + kk * 32 + g * 8);
#pragma unroll
            for (int i = 0; i < 4; ++i)
                bv[i] = *(const bf16x8*)(Bs + (wc + i * 16 + r) * 64 + kk * 32 + g * 8);
#pragma unroll
            for (int mi = 0; mi < 4; ++mi)
#pragma unroll
                for (int ni = 0; ni < 4; ++ni)
                    acc[mi][ni] = __builtin_amdgcn_mfma_f32_16x16x32_bf16(
                        av[mi], bv[ni], acc[mi][ni], 0, 0, 0);
        }
        __syncthreads();
    }

    const int crow0 = m0 + wr + g * 4;
    const int ccol0 = n0 + wc + r;
#pragma unroll
    for (int mi = 0; mi < 4; ++mi) {
#pragma unroll
        for (int ni = 0; ni < 4; ++ni) {
            int col = ccol0 + ni * 16;
            float bval = (EPI == 2) ? bias[col] : 0.f;
#pragma unroll
            for (int j = 0; j < 4; ++j) {
                int row = crow0 + mi * 16 + j;
                float v = acc[mi][ni][j];
                if (EPI == 0) {
                    ((unsigned short*)Cv)[(size_t)row * N + col] = f2bf(v);
                } else if (EPI == 1) {
                    ((float*)Cv)[(size_t)row * N + col] = v;
                } else {
                    v = fmaxf(v + bval, 0.f);
                    ((unsigned short*)Cv)[(size_t)row * N + col] = f2bf(v);
                }
            }
        }
    }
}

// ---------- fp32 -> bf16 convert ----------
__global__ __launch_bounds__(256) void cvt_kernel(
    const float* __restrict__ in, unsigned short* __restrict__ out, int n4) {
    int idx = blockIdx.x * 256 + threadIdx.x;
    if (idx >= n4) return;
    float4 v = *(const float4*)(in + (size_t)idx * 4);
    ushort4 u = make_ushort4(f2bf(v.x), f2bf(v.y), f2bf(v.z), f2bf(v.w));
    *(ushort4*)(out + (size_t)idx * 4) = u;
}

// ---------- energy[n,s,p=i*16+j] = (1/8) * dot64(Q[n,s,i], K[n,s,j]) ----------
// QKV layout: row (n*2048+s) x 3072, Q cols 0..1023, K 1024..2047, V 2048..3071
__global__ __launch_bounds__(256) void energy_kernel(
    const unsigned short* __restrict__ QKV, float* __restrict__ E) {
    __shared__ __attribute__((aligned(16))) unsigned short Qs[8 * 1024];
    __shared__ __attribute__((aligned(16))) unsigned short Ks[8 * 1024];
    const int tid = threadIdx.x;
    const int n = blockIdx.y;
    const int s0 = blockIdx.x * 8;
#pragma unroll
    for (int c = 0; c < 4; ++c) {
        int e = c * 2048 + tid * 8;
        int row = e >> 10, col = e & 1023;
        int jj = col >> 6, db = (col >> 3) & 7;
        int sw = jj * 64 + (((db + jj) & 7) << 3);  // rotation swizzle vs 128B-stride conflicts
        size_t gbase = (size_t)(n * 2048 + s0 + row) * 3072;
        *(us8*)(Qs + row * 1024 + sw) = *(const us8*)(QKV + gbase + col);
        *(us8*)(Ks + row * 1024 + sw) = *(const us8*)(QKV + gbase + 1024 + col);
    }
    __syncthreads();
    const int i = tid >> 4, j = tid & 15;
#pragma unroll
    for (int s = 0; s < 8; ++s) {
        float acc = 0.f;
#pragma unroll
        for (int d8 = 0; d8 < 8; ++d8) {
            us8 q = *(const us8*)(Qs + s * 1024 + i * 64 + (((d8 + i) & 7) << 3));
            us8 k = *(const us8*)(Ks + s * 1024 + j * 64 + (((d8 + j) & 7) << 3));
#pragma unroll
            for (int t = 0; t < 8; ++t) acc += bf2f(q[t]) * bf2f(k[t]);
        }
        E[(size_t)(n * 2048 + s0 + s) * 256 + tid] = acc * 0.125f;
    }
}

// ---------- softmax-over-s stats, stage 1: per-128-chunk online (m, z) ----------
__global__ __launch_bounds__(256) void smax_part(
    const float* __restrict__ E, float* __restrict__ Mp, float* __restrict__ Zp) {
    const int p = threadIdx.x, n = blockIdx.y, sc = blockIdx.x;
    float m = -1e30f, z = 0.f;
    const float* base = E + ((size_t)n * 2048 + sc * 128) * 256 + p;
    for (int s = 0; s < 128; ++s) {
        float e = base[(size_t)s * 256];
        float mn = fmaxf(m, e);
        z = z * __expf(m - mn) + __expf(e - mn);
        m = mn;
    }
    int idx = (n * 16 + sc) * 256 + p;
    Mp[idx] = m;
    Zp[idx] = z;
}

// ---------- stats stage 2: combine 16 chunks -> M, 1/Z ----------
__global__ __launch_bounds__(256) void smax_fin(
    const float* __restrict__ Mp, const float* __restrict__ Zp,
    float* __restrict__ Mf, float* __restrict__ RZf) {
    const int p = threadIdx.x, n = blockIdx.x;
    float m = -1e30f;
    for (int c = 0; c < 16; ++c) m = fmaxf(m, Mp[(n * 16 + c) * 256 + p]);
    float z = 0.f;
    for (int c = 0; c < 16; ++c)
        z += Zp[(n * 16 + c) * 256 + p] * __expf(Mp[(n * 16 + c) * 256 + p] - m);
    Mf[n * 256 + p] = m;
    RZf[n * 256 + p] = 1.f / z;
}

// ---------- attn_src[n, h*128+s/16, (s%16)*64+d] = A[n,h,s] * Vs[n,s,d] ----------
__global__ __launch_bounds__(256) void attnsrc_kernel(
    const unsigned short* __restrict__ QKV, const float* __restrict__ E,
    const float* __restrict__ Mf, const float* __restrict__ RZf,
    unsigned short* __restrict__ ASRC) {
    const int lane = threadIdx.x & 63;
    const int widx = blockIdx.x * 4 + (threadIdx.x >> 6);
    const int n = widx >> 11, s = widx & 2047;
    // Vs[d=lane] = sum over 16 heads of V
    float vs = 0.f;
    const unsigned short* vrow = QKV + (size_t)(n * 2048 + s) * 3072 + 2048;
#pragma unroll
    for (int h = 0; h < 16; ++h) vs += bf2f(vrow[h * 64 + lane]);
    // A[h] on lanes 0..15
    float aval = 0.f;
    if (lane < 16) {
        const float* erow = E + (size_t)(n * 2048 + s) * 256 + lane * 16;
        const float* mrow = Mf + n * 256 + lane * 16;
        const float* zrow = RZf + n * 256 + lane * 16;
#pragma unroll
        for (int j = 0; j < 16; ++j)
            aval += __expf(erow[j] - mrow[j]) * zrow[j];
    }
#pragma unroll
    for (int h = 0; h < 16; ++h) {
        float ah = __shfl(aval, h, 64);
        size_t row = (size_t)n * 2048 + h * 128 + (s >> 4);
        ASRC[row * 1024 + (s & 15) * 64 + lane] = f2bf(ah * vs);
    }
}

// ---------- LayerNorm(lin + bias + resid) * w + b -> bf16 and/or fp32 ----------
__global__ __launch_bounds__(256) void ln_kernel(
    const float* __restrict__ lin, const float* __restrict__ bias,
    const float* __restrict__ resid, const float* __restrict__ w,
    const float* __restrict__ b, unsigned short* __restrict__ obf,
    float* __restrict__ of) {
    __shared__ float sm[16];
    const int row = blockIdx.x, c = threadIdx.x * 4;
    const size_t off = (size_t)row * 1024 + c;
    float4 v = *(const float4*)(lin + off);
    float4 bs = *(const float4*)(bias + c);
    float4 rx = *(const float4*)(resid + off);
    float t0 = v.x + bs.x + rx.x;
    float t1 = v.y + bs.y + rx.y;
    float t2 = v.z + bs.z + rx.z;
    float t3 = v.w + bs.w + rx.w;
    float s = t0 + t1 + t2 + t3;
    float ss = t0 * t0 + t1 * t1 + t2 * t2 + t3 * t3;
#pragma unroll
    for (int o = 32; o > 0; o >>= 1) {
        s += __shfl_down(s, o, 64);
        ss += __shfl_down(ss, o, 64);
    }
    const int wv = threadIdx.x >> 6, ln = threadIdx.x & 63;
    if (ln == 0) {
        sm[wv] = s;
        sm[8 + wv] = ss;
    }
    __syncthreads();
    if (threadIdx.x == 0) {
        sm[4] = sm[0] + sm[1] + sm[2] + sm[3];
        sm[12] = sm[8] + sm[9] + sm[10] + sm[11];
    }
    __syncthreads();
    s = sm[4];
    ss = sm[12];
    float mean = s * (1.f / 1024.f);
    float var = ss * (1.f / 1024.f) - mean * mean;
    float rstd = rsqrtf(var + 1e-5f);
    float4 wv4 = *(const float4*)(w + c);
    float4 bv4 = *(const float4*)(b + c);
    float o0 = (t0 - mean) * rstd * wv4.x + bv4.x;
    float o1 = (t1 - mean) * rstd * wv4.y + bv4.y;
    float o2 = (t2 - mean) * rstd * wv4.z + bv4.z;
    float o3 = (t3 - mean) * rstd * wv4.w + bv4.w;
    if (of) {
        float4 o = make_float4(o0, o1, o2, o3);
        *(float4*)(of + off) = o;
    }
    if (obf) {
        ushort4 u = make_ushort4(f2bf(o0), f2bf(o1), f2bf(o2), f2bf(o3));
        *(ushort4*)(obf + off) = u;
    }
}

// ---------- launch ----------
extern "C" void kernel_launch(void* const* d_in, const int* in_sizes, int n_in,
                              void* d_out, int out_size, void* d_ws, size_t ws_size,
                              hipStream_t stream) {
    const float* x = (const float*)d_in[0];
    const float* Wq = (const float*)d_in[1];
    const float* Wk = (const float*)d_in[2];
    const float* Wv = (const float*)d_in[3];
    const float* Wo = (const float*)d_in[4];
    const float* bo = (const float*)d_in[5];
    const float* ln1w = (const float*)d_in[6];
    const float* ln1b = (const float*)d_in[7];
    const float* ln2w = (const float*)d_in[8];
    const float* ln2b = (const float*)d_in[9];
    const float* W1 = (const float*)d_in[10];
    const float* bf1 = (const float*)d_in[11];
    const float* W2 = (const float*)d_in[12];
    const float* bf2 = (const float*)d_in[13];

    char* ws = (char*)d_ws;
    const size_t MB = 1u << 20;
    unsigned short* W1bf = (unsigned short*)(ws + 0);        // 8 MB
    unsigned short* W2bf = (unsigned short*)(ws + 8 * MB);   // 8 MB
    unsigned short* x1bf = (unsigned short*)(ws + 16 * MB);  // 16 MB
    float* x1f = (float*)(ws + 32 * MB);                     // 32 MB
    float* ffb = (float*)(ws + 64 * MB);                     // 32 MB
    unsigned short* xbf = (unsigned short*)(ws + 96 * MB);   // 16 MB
    unsigned short* Wqkvbf = (unsigned short*)(ws + 112 * MB);  // 6 MB
    unsigned short* Wobf = (unsigned short*)(ws + 118 * MB);    // 2 MB
    unsigned short* QKV = (unsigned short*)(ws + 120 * MB);     // 48 MB
    float* EN = (float*)(ws + 168 * MB);                        // 8 MB
    float* Mp = (float*)(ws + 176 * MB);
    float* Zp = (float*)(ws + 176 * MB + 128 * 1024);
    float* Mfin = (float*)(ws + 176 * MB + 256 * 1024);
    float* RZfin = (float*)(ws + 176 * MB + 272 * 1024);
    unsigned short* ASRC = (unsigned short*)(ws + 177 * MB);  // 16 MB -> peak 193 MB
    float* ALIN = (float*)(ws + 120 * MB);                    // reuse QKV region
    unsigned short* H1 = (unsigned short*)(ws + 96 * MB);     // reuse front pool (64 MB)

    auto cvt = [&](const float* src, unsigned short* dst, int n) {
        int n4 = n >> 2;
        cvt_kernel<<<dim3((n4 + 255) / 256), dim3(256), 0, stream>>>(src, dst, n4);
    };
    cvt(x, xbf, 8192 * 1024);
    cvt(Wq, Wqkvbf, 1024 * 1024);
    cvt(Wk, Wqkvbf + 1024 * 1024, 1024 * 1024);
    cvt(Wv, Wqkvbf + 2 * 1024 * 1024, 1024 * 1024);
    cvt(Wo, Wobf, 1024 * 1024);
    cvt(W1, W1bf, 4096 * 1024);
    cvt(W2, W2bf, 4096 * 1024);

    // QKV = xbf @ [Wq;Wk;Wv]^T  (8192 x 3072)
    gemm_bt<0><<<dim3(24, 64), 256, 0, stream>>>(xbf, Wqkvbf, QKV, nullptr, 8192, 3072, 1024);
    // energy (n,s,256)
    energy_kernel<<<dim3(256, 4), 256, 0, stream>>>(QKV, EN);
    // softmax stats over s
    smax_part<<<dim3(16, 4), 256, 0, stream>>>(EN, Mp, Zp);
    smax_fin<<<dim3(4), 256, 0, stream>>>(Mp, Zp, Mfin, RZfin);
    // attn_src = scrambled A*Vs (8192 x 1024 bf16)
    attnsrc_kernel<<<dim3(2048), 256, 0, stream>>>(QKV, EN, Mfin, RZfin, ASRC);
    // attn_lin = attn_src @ Wo^T (fp32)
    gemm_bt<1><<<dim3(8, 64), 256, 0, stream>>>(ASRC, Wobf, ALIN, nullptr, 8192, 1024, 1024);
    // x1 = LN1(attn_lin + bo + x)
    ln_kernel<<<dim3(8192), 256, 0, stream>>>(ALIN, bo, x, ln1w, ln1b, x1bf, x1f);
    // H1 = relu(x1 @ W1^T + bf1) (bf16)
    gemm_bt<2><<<dim3(32, 64), 256, 0, stream>>>(x1bf, W1bf, H1, bf1, 8192, 4096, 1024);
    // ff = H1 @ W2^T (fp32)
    gemm_bt<1><<<dim3(8, 64), 256, 0, stream>>>(H1, W2bf, ffb, nullptr, 8192, 1024, 4096);
    // out = LN2(ff + bf2 + x1)
    ln_kernel<<<dim3(8192), 256, 0, stream>>>(ffb, bf2, x1f, ln2w, ln2b, nullptr, (float*)d_out);
}

// Round 3
// 460.765 us; speedup vs baseline: 1.0460x; 1.0460x over previous
//
#include <hip/hip_runtime.h>

// ---------- types ----------
typedef __attribute__((ext_vector_type(8))) __bf16 bf16x8;
typedef __attribute__((ext_vector_type(8))) unsigned short us8;
typedef __attribute__((ext_vector_type(4))) float f32x4;

#define DEV __device__ __forceinline__

DEV unsigned short f2bf(float f) {
    unsigned u = __builtin_bit_cast(unsigned, f);
    u += 0x7fffu + ((u >> 16) & 1u);
    return (unsigned short)(u >> 16);
}
DEV float bf2f(unsigned short h) {
    return __builtin_bit_cast(float, (unsigned)h << 16);
}

DEV void gload_lds16(const void* g, void* l) {
    __builtin_amdgcn_global_load_lds(
        (const __attribute__((address_space(1))) unsigned int*)g,
        (__attribute__((address_space(3))) unsigned int*)l, 16, 0, 0);
}

#define VMCNT8 asm volatile("s_waitcnt vmcnt(8)" ::: "memory")
#define VMCNT0 asm volatile("s_waitcnt vmcnt(0)" ::: "memory")
#define BAR __builtin_amdgcn_s_barrier()

// ---------- 256x256 8-phase GEMM: C[M,N] = A[M,K_slice] * B[N,K_slice]^T ----------
// bf16 in, fp32 acc. EPI 0: bf16 store; 1: fp32 store (per-z partial); 2: relu(x+bias) bf16.
// 8 waves (2M x 4N), per-wave 128x64 output, BK=64, 128 KiB LDS double buffer.
// LDS swizzle: 16B slot ^= (row&7); inverse-swizzled global source col (linear
// global_load_lds dest) + swizzled ds_read addr (rule #21: both-sides).
// Counted vmcnt (T4): raw s_barrier ONLY in the K-loop — __syncthreads would
// drain vmcnt(0) and kill the pipeline (m218: -38..-73%).
template <int EPI>
__global__ __launch_bounds__(512) void gemm256(
    const unsigned short* __restrict__ A, const unsigned short* __restrict__ B,
    void* __restrict__ Cv, const float* __restrict__ bias,
    int lda, int ldb, int N, int Kslice) {
    extern __shared__ char smem[];  // [2 buf][A 32K | B 32K]
    const int t = threadIdx.x;
    const int m0 = blockIdx.y * 256;
    const int n0 = blockIdx.x * 256;
    const int z = blockIdx.z;
    const unsigned short* Ag = A + (size_t)z * Kslice;
    const unsigned short* Bg = B + (size_t)z * Kslice;
    const int NT = Kslice >> 6;

    // staging chunk precompute: 4 A-chunks + 4 B-chunks per thread (16B each)
    size_t aoff[4], boff[4];
    int ldb_off[4];
#pragma unroll
    for (int j = 0; j < 4; ++j) {
        int cj = j * 512 + t;
        int row = cj >> 3, slot = cj & 7;
        int col = (slot ^ (row & 7)) << 3;  // inverse-swizzled source column (elements)
        aoff[j] = (size_t)(m0 + row) * lda + col;
        boff[j] = (size_t)(n0 + row) * ldb + col;
        ldb_off[j] = cj << 4;  // linear LDS byte offset (wave-uniform base + lane*16)
    }

    // fragment read precompute
    const int lane = t & 63, r = lane & 15, g = lane >> 4;
    const int wid = t >> 6, wm = wid >> 2, wn = wid & 3;
    const int s0 = (g ^ (r & 7)) << 4;  // swizzled 16B slot byte for kk=0; kk=1 -> ^0x40
    const int aRow = (wm * 128 + r) * 128;
    const int bRow = (wn * 64 + r) * 128;

#define LDA8(base, mi, kk) \
    (*(const bf16x8*)((base) + aRow + (mi) * 2048 + (s0 ^ ((kk) << 6))))
#define LDB8(base, ni, kk) \
    (*(const bf16x8*)((base) + 32768 + bRow + (ni) * 2048 + (s0 ^ ((kk) << 6))))

#define STAGE(base, kt)                                                       \
    do {                                                                      \
        const unsigned short* _as = Ag + (size_t)(kt) * 64;                   \
        const unsigned short* _bs = Bg + (size_t)(kt) * 64;                   \
        _Pragma("unroll") for (int j = 0; j < 4; ++j)                         \
            gload_lds16(_as + aoff[j], (base) + ldb_off[j]);                  \
        _Pragma("unroll") for (int j = 0; j < 4; ++j)                         \
            gload_lds16(_bs + boff[j], (base) + 32768 + ldb_off[j]);          \
    } while (0)

#define PHASE_BODY(MH)                                                        \
    BAR;                                                                      \
    asm volatile("s_waitcnt lgkmcnt(0)" ::: "memory");                        \
    __builtin_amdgcn_sched_barrier(0);                                        \
    __builtin_amdgcn_s_setprio(1);                                            \
    _Pragma("unroll") for (int q = 0; q < 4; ++q)                             \
        _Pragma("unroll") for (int ni = 0; ni < 4; ++ni)                      \
            acc[(MH) * 4 + q][ni] = __builtin_amdgcn_mfma_f32_16x16x32_bf16(  \
                af[q], bfr[ni], acc[(MH) * 4 + q][ni], 0, 0, 0);              \
    __builtin_amdgcn_s_setprio(0);

    // phases per K-tile: (kk0,mh0):12 reads, (kk0,mh1):4, (kk1,mh0):12, (kk1,mh1):4
    // every MFMA cluster bracketed by raw barriers; trailing BAR = WAR protection
    // before the next STAGE overwrites this buffer.
#define COMPUTE_TILE(base)                                                    \
    do {                                                                      \
        _Pragma("unroll") for (int kk = 0; kk < 2; ++kk) {                    \
            bf16x8 bfr[4], af[4];                                             \
            _Pragma("unroll") for (int ni = 0; ni < 4; ++ni)                  \
                bfr[ni] = LDB8(base, ni, kk);                                 \
            _Pragma("unroll") for (int q = 0; q < 4; ++q)                     \
                af[q] = LDA8(base, q, kk);                                    \
            PHASE_BODY(0)                                                     \
            BAR;                                                              \
            _Pragma("unroll") for (int q = 0; q < 4; ++q)                     \
                af[q] = LDA8(base, 4 + q, kk);                                \
            PHASE_BODY(1)                                                     \
        }                                                                     \
        BAR;                                                                  \
    } while (0)

    f32x4 acc[8][4] = {};
    char* buf0 = smem;
    char* buf1 = smem + 65536;

    // prologue: tile0 -> buf0, tile1 -> buf1; wait tile0 only (8 newest in flight)
    STAGE(buf0, 0);
    STAGE(buf1, 1);
    VMCNT8;
    BAR;

    for (int kt = 0; kt < NT; kt += 2) {
        COMPUTE_TILE(buf0);  // trailing BAR: all waves' buf0 reads retired
        if (kt + 2 < NT) {
            STAGE(buf0, kt + 2);  // issue next even tile; wait only the odd tile's 8
            VMCNT8;
        } else {
            VMCNT0;
        }
        BAR;
        COMPUTE_TILE(buf1);
        if (kt + 3 < NT) {
            STAGE(buf1, kt + 3);
            VMCNT8;
        } else {
            VMCNT0;
        }
        BAR;
    }

    // epilogue: C-layout col=lane&15, row=(lane>>4)*4+j (verified mapping)
    const int crow0 = m0 + wm * 128 + g * 4;
    const int ccol0 = n0 + wn * 64 + r;
    float* Cp = (float*)Cv + (size_t)gridDim.y * 256 * N * z;
#pragma unroll
    for (int mi = 0; mi < 8; ++mi) {
#pragma unroll
        for (int ni = 0; ni < 4; ++ni) {
            int col = ccol0 + ni * 16;
            float bval = (EPI == 2) ? bias[col] : 0.f;
#pragma unroll
            for (int j = 0; j < 4; ++j) {
                int row = crow0 + mi * 16 + j;
                float v = acc[mi][ni][j];
                if (EPI == 0) {
                    ((unsigned short*)Cv)[(size_t)row * N + col] = f2bf(v);
                } else if (EPI == 1) {
                    Cp[(size_t)row * N + col] = v;
                } else {
                    v = fmaxf(v + bval, 0.f);
                    ((unsigned short*)Cv)[(size_t)row * N + col] = f2bf(v);
                }
            }
        }
    }
#undef LDA8
#undef LDB8
#undef STAGE
#undef PHASE_BODY
#undef COMPUTE_TILE
}

// ---------- fp32 -> bf16 convert ----------
__global__ __launch_bounds__(256) void cvt_kernel(
    const float* __restrict__ in, unsigned short* __restrict__ out, int n4) {
    int idx = blockIdx.x * 256 + threadIdx.x;
    if (idx >= n4) return;
    float4 v = *(const float4*)(in + (size_t)idx * 4);
    ushort4 u = make_ushort4(f2bf(v.x), f2bf(v.y), f2bf(v.z), f2bf(v.w));
    *(ushort4*)(out + (size_t)idx * 4) = u;
}

// ---------- energy[n,s,p=i*16+j] = (1/8) * dot64(Q[n,s,i], K[n,s,j]) ----------
__global__ __launch_bounds__(256) void energy_kernel(
    const unsigned short* __restrict__ QKV, float* __restrict__ E) {
    __shared__ __attribute__((aligned(16))) unsigned short Qs[8 * 1024];
    __shared__ __attribute__((aligned(16))) unsigned short Ks[8 * 1024];
    const int tid = threadIdx.x;
    const int n = blockIdx.y;
    const int s0 = blockIdx.x * 8;
#pragma unroll
    for (int c = 0; c < 4; ++c) {
        int e = c * 2048 + tid * 8;
        int row = e >> 10, col = e & 1023;
        int jj = col >> 6, db = (col >> 3) & 7;
        int sw = jj * 64 + (((db + jj) & 7) << 3);
        size_t gbase = (size_t)(n * 2048 + s0 + row) * 3072;
        *(us8*)(Qs + row * 1024 + sw) = *(const us8*)(QKV + gbase + col);
        *(us8*)(Ks + row * 1024 + sw) = *(const us8*)(QKV + gbase + 1024 + col);
    }
    __syncthreads();
    const int i = tid >> 4, j = tid & 15;
#pragma unroll
    for (int s = 0; s < 8; ++s) {
        float acc = 0.f;
#pragma unroll
        for (int d8 = 0; d8 < 8; ++d8) {
            us8 q = *(const us8*)(Qs + s * 1024 + i * 64 + (((d8 + i) & 7) << 3));
            us8 k = *(const us8*)(Ks + s * 1024 + j * 64 + (((d8 + j) & 7) << 3));
#pragma unroll
            for (int t = 0; t < 8; ++t) acc += bf2f(q[t]) * bf2f(k[t]);
        }
        E[(size_t)(n * 2048 + s0 + s) * 256 + tid] = acc * 0.125f;
    }
}

// ---------- softmax-over-s stats ----------
__global__ __launch_bounds__(256) void smax_part(
    const float* __restrict__ E, float* __restrict__ Mp, float* __restrict__ Zp) {
    const int p = threadIdx.x, n = blockIdx.y, sc = blockIdx.x;
    float m = -1e30f, z = 0.f;
    const float* base = E + ((size_t)n * 2048 + sc * 128) * 256 + p;
    for (int s = 0; s < 128; ++s) {
        float e = base[(size_t)s * 256];
        float mn = fmaxf(m, e);
        z = z * __expf(m - mn) + __expf(e - mn);
        m = mn;
    }
    int idx = (n * 16 + sc) * 256 + p;
    Mp[idx] = m;
    Zp[idx] = z;
}

__global__ __launch_bounds__(256) void smax_fin(
    const float* __restrict__ Mp, const float* __restrict__ Zp,
    float* __restrict__ Mf, float* __restrict__ RZf) {
    const int p = threadIdx.x, n = blockIdx.x;
    float m = -1e30f;
    for (int c = 0; c < 16; ++c) m = fmaxf(m, Mp[(n * 16 + c) * 256 + p]);
    float z = 0.f;
    for (int c = 0; c < 16; ++c)
        z += Zp[(n * 16 + c) * 256 + p] * __expf(Mp[(n * 16 + c) * 256 + p] - m);
    Mf[n * 256 + p] = m;
    RZf[n * 256 + p] = 1.f / z;
}

// ---------- attn_src[n, h*128+s/16, (s%16)*64+d] = A[n,h,s] * Vs[n,s,d] ----------
__global__ __launch_bounds__(256) void attnsrc_kernel(
    const unsigned short* __restrict__ QKV, const float* __restrict__ E,
    const float* __restrict__ Mf, const float* __restrict__ RZf,
    unsigned short* __restrict__ ASRC) {
    const int lane = threadIdx.x & 63;
    const int widx = blockIdx.x * 4 + (threadIdx.x >> 6);
    const int n = widx >> 11, s = widx & 2047;
    float vs = 0.f;
    const unsigned short* vrow = QKV + (size_t)(n * 2048 + s) * 3072 + 2048;
#pragma unroll
    for (int h = 0; h < 16; ++h) vs += bf2f(vrow[h * 64 + lane]);
    float aval = 0.f;
    if (lane < 16) {
        const float* erow = E + (size_t)(n * 2048 + s) * 256 + lane * 16;
        const float* mrow = Mf + n * 256 + lane * 16;
        const float* zrow = RZf + n * 256 + lane * 16;
#pragma unroll
        for (int j = 0; j < 16; ++j)
            aval += __expf(erow[j] - mrow[j]) * zrow[j];
    }
#pragma unroll
    for (int h = 0; h < 16; ++h) {
        float ah = __shfl(aval, h, 64);
        size_t row = (size_t)n * 2048 + h * 128 + (s >> 4);
        ASRC[row * 1024 + (s & 15) * 64 + lane] = f2bf(ah * vs);
    }
}

// ---------- LayerNorm(lin [+ lin2] + bias + resid) * w + b ----------
__global__ __launch_bounds__(256) void ln_kernel(
    const float* __restrict__ lin, const float* __restrict__ lin2,
    const float* __restrict__ bias, const float* __restrict__ resid,
    const float* __restrict__ w, const float* __restrict__ b,
    unsigned short* __restrict__ obf, float* __restrict__ of) {
    __shared__ float sm[16];
    const int row = blockIdx.x, c = threadIdx.x * 4;
    const size_t off = (size_t)row * 1024 + c;
    float4 v = *(const float4*)(lin + off);
    float4 bs = *(const float4*)(bias + c);
    float4 rx = *(const float4*)(resid + off);
    float t0 = v.x + bs.x + rx.x;
    float t1 = v.y + bs.y + rx.y;
    float t2 = v.z + bs.z + rx.z;
    float t3 = v.w + bs.w + rx.w;
    if (lin2) {
        float4 v2 = *(const float4*)(lin2 + off);
        t0 += v2.x; t1 += v2.y; t2 += v2.z; t3 += v2.w;
    }
    float s = t0 + t1 + t2 + t3;
    float ss = t0 * t0 + t1 * t1 + t2 * t2 + t3 * t3;
#pragma unroll
    for (int o = 32; o > 0; o >>= 1) {
        s += __shfl_down(s, o, 64);
        ss += __shfl_down(ss, o, 64);
    }
    const int wv = threadIdx.x >> 6, ln = threadIdx.x & 63;
    if (ln == 0) {
        sm[wv] = s;
        sm[8 + wv] = ss;
    }
    __syncthreads();
    if (threadIdx.x == 0) {
        sm[4] = sm[0] + sm[1] + sm[2] + sm[3];
        sm[12] = sm[8] + sm[9] + sm[10] + sm[11];
    }
    __syncthreads();
    s = sm[4];
    ss = sm[12];
    float mean = s * (1.f / 1024.f);
    float var = ss * (1.f / 1024.f) - mean * mean;
    float rstd = rsqrtf(var + 1e-5f);
    float4 wv4 = *(const float4*)(w + c);
    float4 bv4 = *(const float4*)(b + c);
    float o0 = (t0 - mean) * rstd * wv4.x + bv4.x;
    float o1 = (t1 - mean) * rstd * wv4.y + bv4.y;
    float o2 = (t2 - mean) * rstd * wv4.z + bv4.z;
    float o3 = (t3 - mean) * rstd * wv4.w + bv4.w;
    if (of) {
        float4 o = make_float4(o0, o1, o2, o3);
        *(float4*)(of + off) = o;
    }
    if (obf) {
        ushort4 u = make_ushort4(f2bf(o0), f2bf(o1), f2bf(o2), f2bf(o3));
        *(ushort4*)(obf + off) = u;
    }
}

// ---------- launch ----------
extern "C" void kernel_launch(void* const* d_in, const int* in_sizes, int n_in,
                              void* d_out, int out_size, void* d_ws, size_t ws_size,
                              hipStream_t stream) {
    const float* x = (const float*)d_in[0];
    const float* Wq = (const float*)d_in[1];
    const float* Wk = (const float*)d_in[2];
    const float* Wv = (const float*)d_in[3];
    const float* Wo = (const float*)d_in[4];
    const float* bo = (const float*)d_in[5];
    const float* ln1w = (const float*)d_in[6];
    const float* ln1b = (const float*)d_in[7];
    const float* ln2w = (const float*)d_in[8];
    const float* ln2b = (const float*)d_in[9];
    const float* W1 = (const float*)d_in[10];
    const float* bf1 = (const float*)d_in[11];
    const float* W2 = (const float*)d_in[12];
    const float* bf2 = (const float*)d_in[13];

    char* ws = (char*)d_ws;
    const size_t MB = 1u << 20;
    // region map (MB), lifetimes annotated:
    unsigned short* W1bf = (unsigned short*)(ws + 0);          // [1..8]
    unsigned short* W2bf = (unsigned short*)(ws + 8 * MB);     // [1..9]
    unsigned short* Wobf = (unsigned short*)(ws + 16 * MB);    // [1..6]
    unsigned short* Wqkvbf = (unsigned short*)(ws + 18 * MB);  // [1..2]
    float* Mp = (float*)(ws + 24 * MB);                        // [4]
    float* Zp = (float*)(ws + 24 * MB + 64 * 1024);            // [4]
    float* Mfin = (float*)(ws + 24 * MB + 128 * 1024);         // [4..5]
    float* RZfin = (float*)(ws + 24 * MB + 160 * 1024);        // [4..5]
    float* x1f = (float*)(ws + 16 * MB);                       // [7..10] (over Wobf/Wqkv/stats)
    unsigned short* ASRC = (unsigned short*)(ws + 48 * MB);    // [5..6]
    unsigned short* x1bf = (unsigned short*)(ws + 48 * MB);    // [7..8] (over ASRC)
    float* AL = (float*)(ws + 64 * MB);                        // [6..7] (z0:64-96, z1:96-128)
    unsigned short* H1 = (unsigned short*)(ws + 64 * MB);      // [8..9] (over AL)
    unsigned short* QKV = (unsigned short*)(ws + 128 * MB);    // [2..5]
    float* FF = (float*)(ws + 128 * MB);                       // [9..10] (over QKV/EN)
    unsigned short* xbf = (unsigned short*)(ws + 176 * MB);    // [1..2]
    float* EN = (float*)(ws + 176 * MB);                       // [3..5] (over xbf)

    // allow 128 KiB dynamic LDS (idempotent; safe under graph capture)
    auto k0 = gemm256<0>; auto k1 = gemm256<1>; auto k2 = gemm256<2>;
    (void)hipFuncSetAttribute((const void*)k0, hipFuncAttributeMaxDynamicSharedMemorySize, 131072);
    (void)hipFuncSetAttribute((const void*)k1, hipFuncAttributeMaxDynamicSharedMemorySize, 131072);
    (void)hipFuncSetAttribute((const void*)k2, hipFuncAttributeMaxDynamicSharedMemorySize, 131072);

    auto cvt = [&](const float* src, unsigned short* dst, int n) {
        int n4 = n >> 2;
        cvt_kernel<<<dim3((n4 + 255) / 256), dim3(256), 0, stream>>>(src, dst, n4);
    };
    cvt(x, xbf, 8192 * 1024);
    cvt(Wq, Wqkvbf, 1024 * 1024);
    cvt(Wk, Wqkvbf + 1024 * 1024, 1024 * 1024);
    cvt(Wv, Wqkvbf + 2 * 1024 * 1024, 1024 * 1024);
    cvt(Wo, Wobf, 1024 * 1024);
    cvt(W1, W1bf, 4096 * 1024);
    cvt(W2, W2bf, 4096 * 1024);

    // 2. QKV = xbf @ [Wq;Wk;Wv]^T  (8192 x 3072, bf16)
    gemm256<0><<<dim3(12, 32, 1), 512, 131072, stream>>>(
        xbf, Wqkvbf, QKV, nullptr, 1024, 1024, 3072, 1024);
    // 3-5. attention (cheap part)
    energy_kernel<<<dim3(256, 4), 256, 0, stream>>>(QKV, EN);
    smax_part<<<dim3(16, 4), 256, 0, stream>>>(EN, Mp, Zp);
    smax_fin<<<dim3(4), 256, 0, stream>>>(Mp, Zp, Mfin, RZfin);
    attnsrc_kernel<<<dim3(2048), 256, 0, stream>>>(QKV, EN, Mfin, RZfin, ASRC);
    // 6. attn_lin = ASRC @ Wo^T, split-K=2 fp32 partials
    gemm256<1><<<dim3(4, 32, 2), 512, 131072, stream>>>(
        ASRC, Wobf, AL, nullptr, 1024, 1024, 1024, 512);
    // 7. x1 = LN1(AL0 + AL1 + bo + x)
    ln_kernel<<<dim3(8192), 256, 0, stream>>>(
        AL, AL + (size_t)8192 * 1024, bo, x, ln1w, ln1b, x1bf, x1f);
    // 8. H1 = relu(x1 @ W1^T + bf1)
    gemm256<2><<<dim3(16, 32, 1), 512, 131072, stream>>>(
        x1bf, W1bf, H1, bf1, 1024, 1024, 4096, 1024);
    // 9. ff = H1 @ W2^T, split-K=2 fp32 partials
    gemm256<1><<<dim3(4, 32, 2), 512, 131072, stream>>>(
        H1, W2bf, FF, nullptr, 4096, 4096, 1024, 2048);
    // 10. out = LN2(ff0 + ff1 + bf2 + x1)
    ln_kernel<<<dim3(8192), 256, 0, stream>>>(
        FF, FF + (size_t)8192 * 1024, bf2, x1f, ln2w, ln2b, nullptr, (float*)d_out);
}